// Round 6
// baseline (537.060 us; speedup 1.0000x reference)
//
#include <hip/hip_runtime.h>
#include <math.h>

#define NN 512
#define KP 64
#define NPANEL 8
#define NTHR 256
#define NBLK 64          // 32 panel + 32 trailing; 1 block/CU (LDS-forced)
#define TRBLK 32
#define TRUNITS (448 * 112)
#define TRTHREADS (TRBLK * NTHR)

// LDS float offsets (25728 floats = 100.5 KB -> 1 block/CU; 64-block grid is
// trivially co-resident on 256 CUs -> manual grid barrier is safe).
// Strides: 65 for scalar-read-by-row tiles, 68 for float4-aligned tiles
// (68%32=4 -> consecutive rows land 4 banks apart; breaks 4-way conflicts).
#define D_   0        // 64 x 65   diag block (state p)
#define V_   4160     // 64 x 65   V-state for substitution
#define B2_  8320     // 64 x 68   Cprev k0-rows tile
#define UB_  12672    // 64 x 68   Rprev k0-cols tile
#define SB_  17024    // 64 x 68   own-slice prev tile
#define H_   21376    // 64 x 68   evolve snapshot history
#define LDSN 25728

__device__ __forceinline__ float einit(const float* s, const float* dI, int i, int j) {
  float w = dI[i * NN + j] / (s[i * NN + j] + 1e-4f);
  if (i == j) w = 0.f;
  return expf(-10.f * w);
}

// Grid barrier, storm-free: RELEASE fetch_add on arrival (one L2 writeback
// per block), RELAXED polling (no cache ops per poll), single ACQUIRE fence
// (one L2 invalidate per block) after the generation flag flips.
__device__ __forceinline__ void gridbar(unsigned* flags, int ph, int tid) {
  __syncthreads();
  if (tid == 0) {
    unsigned v = __hip_atomic_fetch_add(&flags[0], 1u, __ATOMIC_RELEASE,
                                        __HIP_MEMORY_SCOPE_AGENT);
    if (v == (unsigned)NBLK * (unsigned)(ph + 1) - 1u)
      __hip_atomic_store(&flags[1], (unsigned)(ph + 1), __ATOMIC_RELEASE,
                         __HIP_MEMORY_SCOPE_AGENT);
    while (__hip_atomic_load(&flags[1], __ATOMIC_RELAXED,
                             __HIP_MEMORY_SCOPE_AGENT) < (unsigned)(ph + 1))
      __builtin_amdgcn_s_sleep(16);
    __builtin_amdgcn_fence(__ATOMIC_ACQUIRE, "agent");
  }
  __syncthreads();
}

__device__ __forceinline__ float loss_elem(float Ev, float sv, float ov,
                                           float dv, float fv, int i, int j,
                                           float esc) {
  const float sp = (Ev > 0.f) ? (-0.1f * logf(Ev)) : 1e9f;
  const float ur = expf(-0.005f * sp);
  const float ub = expf(-0.01f * dv);
  const float choice = ur / (ur + ub);
  const float ug = fv * choice * (dv - 0.5f * sp);
  const float util = (ug > 0.f) ? (ug + 1.f) : expf(ug);  // elu + 1
  const float ent = sv * (((i == j) ? 1.f : 0.f) - sv);
  return sv * dv + util + esc * ent * ent + 10000.f * (sv * (1.f - ov));
}

__global__ __launch_bounds__(NTHR) void fw_all(
    const float* __restrict__ s, const float* __restrict__ o,
    const float* __restrict__ dI, const float* __restrict__ f,
    const int* __restrict__ ep, float* __restrict__ E,
    float* __restrict__ Cs, float* __restrict__ Rs,
    unsigned* __restrict__ flags, float* __restrict__ out) {
  __shared__ __align__(16) float lds[LDSN];
  const int blk = blockIdx.x, tid = threadIdx.x;
  const bool panel = (blk < 32);
  const bool isC = (blk < 16);
  const int sb = (blk >> 1) & 7;
  const int h = blk & 1;
  const int sOff = sb * KP;

  for (int p = 0; p < NPANEL; ++p) {
    const int k0 = p * KP;
    if (panel) {
      const bool haveSl = (sb != p);
      const float* Cprev = Cs + (size_t)(p - 1) * (NN * KP);
      const float* Rprev = Rs + (size_t)(p - 1) * (KP * NN);
      if (p == 0) {
        // direct init of diag + own slice; write E (blk0 owns diag region)
        for (int e = tid; e < 4096; e += NTHR) {
          const int a = e >> 6, b = e & 63;
          const float v = einit(s, dI, a, b);
          lds[D_ + a * 65 + b] = v;
          if (blk == 0) E[a * NN + b] = v;
        }
        if (haveSl) {
          if (isC) {
            for (int e = tid; e < 2048; e += NTHR) {
              const int a = 32 * h + (e >> 6), b = e & 63;
              const float v = einit(s, dI, sOff + a, b);
              lds[V_ + a * 65 + b] = v;
              E[(sOff + a) * NN + b] = v;
            }
          } else {
            for (int e = tid; e < 2048; e += NTHR) {
              const int m = e >> 5, j = 32 * h + (e & 31);
              const float v = einit(s, dI, m, sOff + j);
              lds[V_ + j * 65 + m] = v;
              E[m * NN + (sOff + j)] = v;
            }
          }
        }
      } else {
        // -------- stage tiles (float4) --------
#pragma unroll
        for (int k = 0; k < 4; ++k) {
          const int e4 = tid + k * NTHR;
          const int a = e4 >> 4, b4 = (e4 & 15) << 2;
          *(float4*)&lds[B2_ + a * 68 + b4] =
              *(const float4*)(Cprev + (size_t)(k0 + a) * KP + b4);
          *(float4*)&lds[UB_ + a * 68 + b4] =
              *(const float4*)(Rprev + (size_t)a * NN + (k0 + b4));
          if (haveSl) {
            if (isC)
              *(float4*)&lds[SB_ + a * 68 + b4] =
                  *(const float4*)(Cprev + (size_t)(sOff + a) * KP + b4);
            else
              *(float4*)&lds[SB_ + a * 68 + b4] =
                  *(const float4*)(Rprev + (size_t)a * NN + (sOff + b4));
          }
        }
        __syncthreads();
        // -------- diag GEMM: D = E[diag] + Ck0 * Rk0 (state p) --------
        {
          const int r0 = (tid >> 4) << 2, m0 = (tid & 15) << 2;
          float acc[4][4];
#pragma unroll
          for (int i2 = 0; i2 < 4; ++i2) {
            const float4 ev = *(const float4*)(E + (size_t)(k0 + r0 + i2) * NN + (k0 + m0));
            acc[i2][0] = ev.x; acc[i2][1] = ev.y; acc[i2][2] = ev.z; acc[i2][3] = ev.w;
          }
          for (int rr = 0; rr < KP; ++rr) {
            const float4 b4 = *(const float4*)&lds[UB_ + rr * 68 + m0];
#pragma unroll
            for (int i2 = 0; i2 < 4; ++i2) {
              const float av = lds[B2_ + (r0 + i2) * 68 + rr];
              acc[i2][0] += av * b4.x; acc[i2][1] += av * b4.y;
              acc[i2][2] += av * b4.z; acc[i2][3] += av * b4.w;
            }
          }
#pragma unroll
          for (int i2 = 0; i2 < 4; ++i2)
#pragma unroll
            for (int j2 = 0; j2 < 4; ++j2)
              lds[D_ + (r0 + i2) * 65 + (m0 + j2)] = acc[i2][j2];
        }
      }
      __syncthreads();

      // ======== concurrent region: wave0 evolve || w1-2 slice GEMM ========
      if (tid < 64) {
        // barrier-free readlane evolve. C-side: lane t holds column t of D;
        // R-side: lane t holds row t (transpose evolves by the same rule).
        float x[64];
        if (isC) {
#pragma unroll
          for (int a = 0; a < 64; ++a) x[a] = lds[D_ + a * 65 + tid];
        } else {
#pragma unroll
          for (int a = 0; a < 64; ++a) x[a] = lds[D_ + tid * 65 + a];
        }
#pragma unroll
        for (int m = 0; m < 64; ++m) {
          const float xm = x[m];
          lds[H_ + m * 68 + tid] = xm;
#pragma unroll
          for (int a = 0; a < 64; ++a) {
            const int sa = __builtin_amdgcn_readlane(__float_as_int(x[a]), m);
            x[a] += __int_as_float(sa) * xm;
          }
        }
      } else if (tid < 192) {
        const int tt = tid - 64;
        if (haveSl && p > 0) {
          // slice GEMM: V = E[slice] + prev rank-64; write corrected E back
          float acc[4][4];
          if (isC) {
            const int r0 = 32 * h + ((tt >> 4) << 2);
            const int m0 = (tt & 15) << 2;
#pragma unroll
            for (int i2 = 0; i2 < 4; ++i2) {
              const float4 ev = *(const float4*)(E + (size_t)(sOff + r0 + i2) * NN + (k0 + m0));
              acc[i2][0] = ev.x; acc[i2][1] = ev.y; acc[i2][2] = ev.z; acc[i2][3] = ev.w;
            }
            for (int rr = 0; rr < KP; ++rr) {
              const float4 b4 = *(const float4*)&lds[UB_ + rr * 68 + m0];
#pragma unroll
              for (int i2 = 0; i2 < 4; ++i2) {
                const float av = lds[SB_ + (r0 + i2) * 68 + rr];
                acc[i2][0] += av * b4.x; acc[i2][1] += av * b4.y;
                acc[i2][2] += av * b4.z; acc[i2][3] += av * b4.w;
              }
            }
#pragma unroll
            for (int i2 = 0; i2 < 4; ++i2) {
              *(float4*)(E + (size_t)(sOff + r0 + i2) * NN + (k0 + m0)) =
                  make_float4(acc[i2][0], acc[i2][1], acc[i2][2], acc[i2][3]);
#pragma unroll
              for (int j2 = 0; j2 < 4; ++j2)
                lds[V_ + (r0 + i2) * 65 + (m0 + j2)] = acc[i2][j2];
            }
          } else {
            const int r0 = (tt & 15) << 2;              // m rows k0+r0..
            const int c0 = 32 * h + ((tt >> 4) << 2);   // slice col band
#pragma unroll
            for (int i2 = 0; i2 < 4; ++i2) {
              const float4 ev = *(const float4*)(E + (size_t)(k0 + r0 + i2) * NN + (sOff + c0));
              acc[i2][0] = ev.x; acc[i2][1] = ev.y; acc[i2][2] = ev.z; acc[i2][3] = ev.w;
            }
            for (int rr = 0; rr < KP; ++rr) {
              const float4 b4 = *(const float4*)&lds[SB_ + rr * 68 + c0];
#pragma unroll
              for (int i2 = 0; i2 < 4; ++i2) {
                const float av = lds[B2_ + (r0 + i2) * 68 + rr];
                acc[i2][0] += av * b4.x; acc[i2][1] += av * b4.y;
                acc[i2][2] += av * b4.z; acc[i2][3] += av * b4.w;
              }
            }
#pragma unroll
            for (int i2 = 0; i2 < 4; ++i2) {
              *(float4*)(E + (size_t)(k0 + r0 + i2) * NN + (sOff + c0)) =
                  make_float4(acc[i2][0], acc[i2][1], acc[i2][2], acc[i2][3]);
#pragma unroll
              for (int j2 = 0; j2 < 4; ++j2)
                lds[V_ + (c0 + j2) * 65 + (r0 + i2)] = acc[i2][j2];
            }
          }
        } else if (!haveSl) {
          // diag slice: V = D (C-side) or D^T (R-side)
          for (int e = tt; e < 4096; e += 128) {
            const int a = e >> 6, b = e & 63;
            lds[V_ + a * 65 + b] = isC ? lds[D_ + a * 65 + b] : lds[D_ + b * 65 + a];
          }
        }
      }
      __syncthreads();

      // -------- chunked forward substitution on V rows [32h, 32h+32) ------
      for (int cch = 0; cch < 4; ++cch) {
        const int mb = cch * 16;
        if (cch > 0 && tid < 128) {
          const int r = 32 * h + (tid & 31);
          const int g = tid >> 5;
          const int m0c = mb + 4 * g;
          const int vb = V_ + r * 65;
          float a0 = lds[vb + m0c + 0], a1 = lds[vb + m0c + 1];
          float a2 = lds[vb + m0c + 2], a3 = lds[vb + m0c + 3];
          for (int mp = 0; mp < mb; ++mp) {
            const float vr = lds[vb + mp];
            const float4 u4 = *(const float4*)&lds[H_ + mp * 68 + m0c];
            a0 += vr * u4.x; a1 += vr * u4.y; a2 += vr * u4.z; a3 += vr * u4.w;
          }
          lds[vb + m0c + 0] = a0; lds[vb + m0c + 1] = a1;
          lds[vb + m0c + 2] = a2; lds[vb + m0c + 3] = a3;
        }
        __syncthreads();
        if (tid < 32) {
          const int r = 32 * h + tid;
          const int vb = V_ + r * 65 + mb;
          float v[16];
#pragma unroll
          for (int u2 = 0; u2 < 16; ++u2) v[u2] = lds[vb + u2];
#pragma unroll
          for (int mp = 0; mp < 15; ++mp) {
            const float vmp = v[mp];
#pragma unroll
            for (int m2 = mp + 1; m2 < 16; ++m2)
              v[m2] += vmp * lds[H_ + (mb + mp) * 68 + (mb + m2)];
          }
#pragma unroll
          for (int u2 = 0; u2 < 16; ++u2) lds[vb + u2] = v[u2];
        }
        __syncthreads();
      }

      // -------- snapshot panel writeout --------
      float* Cp = Cs + (size_t)p * (NN * KP);
      float* Rp = Rs + (size_t)p * (KP * NN);
      if (isC) {
        for (int e = tid; e < 2048; e += NTHR) {
          const int a = 32 * h + (e >> 6), b = e & 63;
          Cp[(size_t)(sOff + a) * KP + b] = lds[V_ + a * 65 + b];
        }
      } else {
        for (int e = tid; e < 2048; e += NTHR) {
          const int m = e >> 5, j = 32 * h + (e & 31);
          Rp[(size_t)m * NN + (sOff + j)] = lds[V_ + j * 65 + m];
        }
      }
    } else {
      // ================= trailing blocks (32, strided) =================
      const int gt0 = (blk - 32) * NTHR + tid;
      if (p == 0) {
        if (blk == 32 && tid == 0) out[0] = 0.f;
        for (int u = gt0; u < TRUNITS; u += TRTHREADS) {
          const int ii = u / 112;
          const int jj = u - ii * 112;
          const int i = ii + KP;
          const int j = (jj + 16) << 2;
          const int idx = i * NN + j;
          const float4 sv = *(const float4*)(s + idx);
          const float4 dv = *(const float4*)(dI + idx);
          float w0 = dv.x / (sv.x + 1e-4f); if (i == j + 0) w0 = 0.f;
          float w1 = dv.y / (sv.y + 1e-4f); if (i == j + 1) w1 = 0.f;
          float w2 = dv.z / (sv.z + 1e-4f); if (i == j + 2) w2 = 0.f;
          float w3 = dv.w / (sv.w + 1e-4f); if (i == j + 3) w3 = 0.f;
          *(float4*)(E + idx) = make_float4(expf(-10.f * w0), expf(-10.f * w1),
                                            expf(-10.f * w2), expf(-10.f * w3));
        }
      } else {
        const float* Cprev = Cs + (size_t)(p - 1) * (NN * KP);
        const float* Rprev = Rs + (size_t)(p - 1) * (KP * NN);
        for (int u = gt0; u < TRUNITS; u += TRTHREADS) {
          const int ii = u / 112;
          const int jj = u - ii * 112;
          const int i = (ii < k0) ? ii : ii + KP;
          const int j = ((jj < (p << 4)) ? jj : jj + 16) << 2;
          const int idx = i * NN + j;
          float4 acc = *(const float4*)(E + idx);
          const float* crow = Cprev + (size_t)i * KP;
          const float* rcol = Rprev + j;
#pragma unroll 8
          for (int r = 0; r < KP; ++r) {
            const float cv = crow[r];
            const float4 rv = *(const float4*)(rcol + (size_t)r * NN);
            acc.x += cv * rv.x; acc.y += cv * rv.y;
            acc.z += cv * rv.z; acc.w += cv * rv.w;
          }
          *(float4*)(E + idx) = acc;
        }
      }
    }
    gridbar(flags, p, tid);
  }

  // ---------------- loss epilogue (all 64 blocks, 4 sweeps) ----------------
  {
    const float* C7 = Cs + (size_t)7 * (NN * KP);
    const float* R7 = Rs + (size_t)7 * (KP * NN);
    const int e = ep[0];
    const float esc = (e < 0) ? 0.f : (e < 10) ? 0.05f : (e < 50) ? 0.1f : 1.f;
    float lsum = 0.f;
    for (int it = 0; it < 4; ++it) {
      const int g = it * (NBLK * NTHR) + blk * NTHR + tid;
      const int idx0 = g * 4;
      const int i = idx0 >> 9;
      const int j = idx0 & (NN - 1);
      float4 acc = *(const float4*)(E + idx0);
      {
        const float* crow = C7 + (size_t)i * KP;
        const float* rcol = R7 + j;
#pragma unroll 8
        for (int r = 0; r < KP; ++r) {
          const float cv = crow[r];
          const float4 rv = *(const float4*)(rcol + (size_t)r * NN);
          acc.x += cv * rv.x; acc.y += cv * rv.y;
          acc.z += cv * rv.z; acc.w += cv * rv.w;
        }
      }
      const int bi = i >> 6, bj = j >> 6;
      if (bi == bj && bi >= 1) {   // diag block: add skipped C_{b-1}R_{b-1}
        const float* cf = Cs + (size_t)(bi - 1) * (NN * KP) + (size_t)i * KP;
        const float* rf = Rs + (size_t)(bi - 1) * (KP * NN) + j;
#pragma unroll 8
        for (int r = 0; r < KP; ++r) {
          const float cv = cf[r];
          const float4 rv = *(const float4*)(rf + (size_t)r * NN);
          acc.x += cv * rv.x; acc.y += cv * rv.y;
          acc.z += cv * rv.z; acc.w += cv * rv.w;
        }
      }
      const float4 sv = *(const float4*)(s + idx0);
      const float4 ov = *(const float4*)(o + idx0);
      const float4 dv = *(const float4*)(dI + idx0);
      const float4 fv = *(const float4*)(f + idx0);
      lsum += loss_elem(acc.x, sv.x, ov.x, dv.x, fv.x, i, j + 0, esc)
            + loss_elem(acc.y, sv.y, ov.y, dv.y, fv.y, i, j + 1, esc)
            + loss_elem(acc.z, sv.z, ov.z, dv.z, fv.z, i, j + 2, esc)
            + loss_elem(acc.w, sv.w, ov.w, dv.w, fv.w, i, j + 3, esc);
    }
    float* red = lds;   // reuse D_ region
    red[tid] = lsum;
    __syncthreads();
#pragma unroll
    for (int st = 128; st > 0; st >>= 1) {
      if (tid < st) red[tid] += red[tid + st];
      __syncthreads();
    }
    if (tid == 0) atomicAdd(out, red[0]);
  }
}

extern "C" void kernel_launch(void* const* d_in, const int* in_sizes, int n_in,
                              void* d_out, int out_size, void* d_ws, size_t ws_size,
                              hipStream_t stream) {
  const float* s = (const float*)d_in[0];   // soft_adj
  const float* o = (const float*)d_in[1];   // original_adj
  const float* d = (const float*)d_in[2];   // distances
  const float* f = (const float*)d_in[3];   // flow
  const int* ep = (const int*)d_in[4];      // epoch

  unsigned* flags = (unsigned*)d_ws;        // flags[0]=arrive cnt, [1]=gen
  float* E = (float*)((char*)d_ws + 256);   // 512*512
  float* Cs = E + NN * NN;                  // 8 x [512*64]
  float* Rs = Cs + NPANEL * NN * KP;        // 8 x [64*512]
  float* out = (float*)d_out;

  hipMemsetAsync(d_ws, 0, 256, stream);     // zero barrier flags every call
  fw_all<<<NBLK, NTHR, 0, stream>>>(s, o, d, f, ep, E, Cs, Rs, flags, out);
}

// Round 7
// 244.547 us; speedup vs baseline: 2.1961x; 2.1961x over previous
//
#include <hip/hip_runtime.h>
#include <math.h>

#define NN 512
#define KP 64
#define NPANEL 8
#define NTHR 256
#define NBLK 256
#define TRUNITS (448 * 112)

// LDS float offsets (25728 floats = 100.5 KB -> 1 block/CU).
// Strides: 65 for scalar-read-by-row tiles (D,V), 68 for float4-aligned
// staged tiles (68%32=4 -> stride-4-row scalar reads land in distinct banks).
#define D_   0        // 64 x 65   diag block (state p)
#define V_   4160     // 64 x 65   V-state for substitution
#define B2_  8320     // 64 x 68   Cprev k0-rows tile
#define UB_  12672    // 64 x 68   Rprev k0-cols tile
#define SB_  17024    // 64 x 68   own-slice prev tile
#define H_   21376    // 64 x 68   evolve snapshot history
#define LDSN 25728

__device__ __forceinline__ float einit(const float* s, const float* dI, int i, int j) {
  float w = dI[i * NN + j] / (s[i * NN + j] + 1e-4f);
  if (i == j) w = 0.f;
  return expf(-10.f * w);
}

// Phase p (one launch per phase; inter-launch barrier = phase sync):
//  blocks 0..31  : panel blocks (8 slices x 2 sides x 2 halves). Stage prev
//    C/R tiles, correct diag + own slice to state p (lazy C_{p-1}R_{p-1}),
//    readlane-evolve diag (wave 0, barrier-free) CONCURRENT with the slice
//    GEMM (waves 1-2), chunked forward substitution -> C_p, R_p.
//  blocks 32..255: trailing rank-64 update of complement(cross(p)) (p>0),
//    or E init there (p==0). One float4 unit per thread.
// Diag block (p,p) never written in-phase; diag b misses exactly
// C_{b-1}R_{b-1}, fixed in k_loss (which also adds C_7R_7).
__global__ __launch_bounds__(NTHR) void fw_phase(
    const float* __restrict__ s, const float* __restrict__ dI,
    float* __restrict__ E, float* __restrict__ Cs, float* __restrict__ Rs,
    float* __restrict__ out, int p) {
  __shared__ __align__(16) float lds[LDSN];
  const int blk = blockIdx.x, tid = threadIdx.x;
  const int k0 = p * KP;

  if (blk >= 32) {
    // ================= trailing blocks =================
    const int gt = (blk - 32) * NTHR + tid;
    if (p == 0) {
      if (blk == 32 && tid == 0) out[0] = 0.f;   // zero loss accumulator
      if (gt < TRUNITS) {
        const int ii = gt / 112;
        const int jj = gt - ii * 112;
        const int i = ii + KP;
        const int j = (jj + 16) << 2;
        const int idx = i * NN + j;
        const float4 sv = *(const float4*)(s + idx);
        const float4 dv = *(const float4*)(dI + idx);
        float w0 = dv.x / (sv.x + 1e-4f); if (i == j + 0) w0 = 0.f;
        float w1 = dv.y / (sv.y + 1e-4f); if (i == j + 1) w1 = 0.f;
        float w2 = dv.z / (sv.z + 1e-4f); if (i == j + 2) w2 = 0.f;
        float w3 = dv.w / (sv.w + 1e-4f); if (i == j + 3) w3 = 0.f;
        *(float4*)(E + idx) = make_float4(expf(-10.f * w0), expf(-10.f * w1),
                                          expf(-10.f * w2), expf(-10.f * w3));
      }
    } else if (gt < TRUNITS) {
      const int ii = gt / 112;
      const int jj = gt - ii * 112;
      const int i = (ii < k0) ? ii : ii + KP;
      const int j = ((jj < (p << 4)) ? jj : jj + 16) << 2;
      const int idx = i * NN + j;
      const float* Cprev = Cs + (size_t)(p - 1) * (NN * KP);
      const float* Rprev = Rs + (size_t)(p - 1) * (KP * NN);
      float4 acc = *(const float4*)(E + idx);
      const float* crow = Cprev + (size_t)i * KP;
      const float* rcol = Rprev + j;
#pragma unroll 8
      for (int r = 0; r < KP; ++r) {
        const float cv = crow[r];
        const float4 rv = *(const float4*)(rcol + (size_t)r * NN);
        acc.x += cv * rv.x; acc.y += cv * rv.y;
        acc.z += cv * rv.z; acc.w += cv * rv.w;
      }
      *(float4*)(E + idx) = acc;
    }
    return;
  }

  // ================= panel blocks =================
  const bool isC = (blk < 16);
  const int sb = (blk >> 1) & 7;
  const int h = blk & 1;                 // half: rows/cols [32h, 32h+32)
  const int sOff = sb * KP;
  const bool haveSl = (sb != p);
  const float* Cprev = Cs + (size_t)(p - 1) * (NN * KP);
  const float* Rprev = Rs + (size_t)(p - 1) * (KP * NN);

  if (p == 0) {
    // direct init of diag + own slice; write E (blk0 owns diag region)
    for (int e = tid; e < 4096; e += NTHR) {
      const int a = e >> 6, b = e & 63;
      const float v = einit(s, dI, a, b);
      lds[D_ + a * 65 + b] = v;
      if (blk == 0) E[a * NN + b] = v;
    }
    if (haveSl) {
      if (isC) {
        for (int e = tid; e < 2048; e += NTHR) {
          const int a = 32 * h + (e >> 6), b = e & 63;
          const float v = einit(s, dI, sOff + a, b);
          lds[V_ + a * 65 + b] = v;
          E[(sOff + a) * NN + b] = v;
        }
      } else {
        for (int e = tid; e < 2048; e += NTHR) {
          const int m = e >> 5, j = 32 * h + (e & 31);
          const float v = einit(s, dI, m, sOff + j);
          lds[V_ + j * 65 + m] = v;
          E[m * NN + (sOff + j)] = v;
        }
      }
    }
  } else {
    // -------- stage tiles (float4, stride-68) --------
#pragma unroll
    for (int k = 0; k < 4; ++k) {
      const int e4 = tid + k * NTHR;
      const int a = e4 >> 4, b4 = (e4 & 15) << 2;
      *(float4*)&lds[B2_ + a * 68 + b4] =
          *(const float4*)(Cprev + (size_t)(k0 + a) * KP + b4);
      *(float4*)&lds[UB_ + a * 68 + b4] =
          *(const float4*)(Rprev + (size_t)a * NN + (k0 + b4));
      if (haveSl) {
        if (isC)
          *(float4*)&lds[SB_ + a * 68 + b4] =
              *(const float4*)(Cprev + (size_t)(sOff + a) * KP + b4);
        else
          *(float4*)&lds[SB_ + a * 68 + b4] =
              *(const float4*)(Rprev + (size_t)a * NN + (sOff + b4));
      }
    }
    __syncthreads();
    // -------- diag GEMM: D = E[diag] + Ck0 * Rk0 (state p) --------
    {
      const int r0 = (tid >> 4) << 2, m0 = (tid & 15) << 2;
      float acc[4][4];
#pragma unroll
      for (int i2 = 0; i2 < 4; ++i2) {
        const float4 ev = *(const float4*)(E + (size_t)(k0 + r0 + i2) * NN + (k0 + m0));
        acc[i2][0] = ev.x; acc[i2][1] = ev.y; acc[i2][2] = ev.z; acc[i2][3] = ev.w;
      }
      for (int rr = 0; rr < KP; ++rr) {
        const float4 b4 = *(const float4*)&lds[UB_ + rr * 68 + m0];
#pragma unroll
        for (int i2 = 0; i2 < 4; ++i2) {
          const float av = lds[B2_ + (r0 + i2) * 68 + rr];
          acc[i2][0] += av * b4.x; acc[i2][1] += av * b4.y;
          acc[i2][2] += av * b4.z; acc[i2][3] += av * b4.w;
        }
      }
#pragma unroll
      for (int i2 = 0; i2 < 4; ++i2)
#pragma unroll
        for (int j2 = 0; j2 < 4; ++j2)
          lds[D_ + (r0 + i2) * 65 + (m0 + j2)] = acc[i2][j2];
    }
  }
  __syncthreads();

  // ======== concurrent region: wave0 evolve || waves1-2 slice GEMM ========
  if (tid < 64) {
    // barrier-free readlane evolve. C-side: lane t holds column t of D;
    // R-side: lane t holds row t (transpose evolves by the same rule).
    float x[64];
    if (isC) {
#pragma unroll
      for (int a = 0; a < 64; ++a) x[a] = lds[D_ + a * 65 + tid];
    } else {
#pragma unroll
      for (int a = 0; a < 64; ++a) x[a] = lds[D_ + tid * 65 + a];
    }
#pragma unroll
    for (int m = 0; m < 64; ++m) {
      const float xm = x[m];
      lds[H_ + m * 68 + tid] = xm;
#pragma unroll
      for (int a = 0; a < 64; ++a) {
        const int sa = __builtin_amdgcn_readlane(__float_as_int(x[a]), m);
        x[a] += __int_as_float(sa) * xm;
      }
    }
  } else if (tid < 192) {
    const int tt = tid - 64;
    if (haveSl && p > 0) {
      // slice GEMM: V = E[slice] + prev rank-64; write corrected E back
      float acc[4][4];
      if (isC) {
        const int r0 = 32 * h + ((tt >> 4) << 2);
        const int m0 = (tt & 15) << 2;
#pragma unroll
        for (int i2 = 0; i2 < 4; ++i2) {
          const float4 ev = *(const float4*)(E + (size_t)(sOff + r0 + i2) * NN + (k0 + m0));
          acc[i2][0] = ev.x; acc[i2][1] = ev.y; acc[i2][2] = ev.z; acc[i2][3] = ev.w;
        }
        for (int rr = 0; rr < KP; ++rr) {
          const float4 b4 = *(const float4*)&lds[UB_ + rr * 68 + m0];
#pragma unroll
          for (int i2 = 0; i2 < 4; ++i2) {
            const float av = lds[SB_ + (r0 + i2) * 68 + rr];
            acc[i2][0] += av * b4.x; acc[i2][1] += av * b4.y;
            acc[i2][2] += av * b4.z; acc[i2][3] += av * b4.w;
          }
        }
#pragma unroll
        for (int i2 = 0; i2 < 4; ++i2) {
          *(float4*)(E + (size_t)(sOff + r0 + i2) * NN + (k0 + m0)) =
              make_float4(acc[i2][0], acc[i2][1], acc[i2][2], acc[i2][3]);
#pragma unroll
          for (int j2 = 0; j2 < 4; ++j2)
            lds[V_ + (r0 + i2) * 65 + (m0 + j2)] = acc[i2][j2];
        }
      } else {
        const int r0 = (tt & 15) << 2;              // m rows k0+r0..
        const int c0 = 32 * h + ((tt >> 4) << 2);   // slice col band
#pragma unroll
        for (int i2 = 0; i2 < 4; ++i2) {
          const float4 ev = *(const float4*)(E + (size_t)(k0 + r0 + i2) * NN + (sOff + c0));
          acc[i2][0] = ev.x; acc[i2][1] = ev.y; acc[i2][2] = ev.z; acc[i2][3] = ev.w;
        }
        for (int rr = 0; rr < KP; ++rr) {
          const float4 b4 = *(const float4*)&lds[SB_ + rr * 68 + c0];
#pragma unroll
          for (int i2 = 0; i2 < 4; ++i2) {
            const float av = lds[B2_ + (r0 + i2) * 68 + rr];
            acc[i2][0] += av * b4.x; acc[i2][1] += av * b4.y;
            acc[i2][2] += av * b4.z; acc[i2][3] += av * b4.w;
          }
        }
#pragma unroll
        for (int i2 = 0; i2 < 4; ++i2) {
          *(float4*)(E + (size_t)(k0 + r0 + i2) * NN + (sOff + c0)) =
              make_float4(acc[i2][0], acc[i2][1], acc[i2][2], acc[i2][3]);
#pragma unroll
          for (int j2 = 0; j2 < 4; ++j2)
            lds[V_ + (c0 + j2) * 65 + (r0 + i2)] = acc[i2][j2];
        }
      }
    } else if (!haveSl) {
      // diag slice: V = D (C-side) or D^T (R-side)
      for (int e = tt; e < 4096; e += 128) {
        const int a = e >> 6, b = e & 63;
        lds[V_ + a * 65 + b] = isC ? lds[D_ + a * 65 + b] : lds[D_ + b * 65 + a];
      }
    }
  }
  __syncthreads();

  // -------- chunked forward substitution on V rows [32h, 32h+32) ------
  for (int cch = 0; cch < 4; ++cch) {
    const int mb = cch * 16;
    if (cch > 0 && tid < 128) {
      const int r = 32 * h + (tid & 31);
      const int g = tid >> 5;
      const int m0c = mb + 4 * g;
      const int vb = V_ + r * 65;
      float a0 = lds[vb + m0c + 0], a1 = lds[vb + m0c + 1];
      float a2 = lds[vb + m0c + 2], a3 = lds[vb + m0c + 3];
      for (int mp = 0; mp < mb; ++mp) {
        const float vr = lds[vb + mp];
        const float4 u4 = *(const float4*)&lds[H_ + mp * 68 + m0c];
        a0 += vr * u4.x; a1 += vr * u4.y; a2 += vr * u4.z; a3 += vr * u4.w;
      }
      lds[vb + m0c + 0] = a0; lds[vb + m0c + 1] = a1;
      lds[vb + m0c + 2] = a2; lds[vb + m0c + 3] = a3;
    }
    __syncthreads();
    if (tid < 32) {
      const int r = 32 * h + tid;
      const int vb = V_ + r * 65 + mb;
      float v[16];
#pragma unroll
      for (int u2 = 0; u2 < 16; ++u2) v[u2] = lds[vb + u2];
#pragma unroll
      for (int mp = 0; mp < 15; ++mp) {
        const float vmp = v[mp];
#pragma unroll
        for (int m2 = mp + 1; m2 < 16; ++m2)
          v[m2] += vmp * lds[H_ + (mb + mp) * 68 + (mb + m2)];
      }
#pragma unroll
      for (int u2 = 0; u2 < 16; ++u2) lds[vb + u2] = v[u2];
    }
    __syncthreads();
  }

  // -------- snapshot panel writeout --------
  float* Cp = Cs + (size_t)p * (NN * KP);
  float* Rp = Rs + (size_t)p * (KP * NN);
  if (isC) {
    for (int e = tid; e < 2048; e += NTHR) {
      const int a = 32 * h + (e >> 6), b = e & 63;
      Cp[(size_t)(sOff + a) * KP + b] = lds[V_ + a * 65 + b];
    }
  } else {
    for (int e = tid; e < 2048; e += NTHR) {
      const int m = e >> 5, j = 32 * h + (e & 31);
      Rp[(size_t)m * NN + (sOff + j)] = lds[V_ + j * 65 + m];
    }
  }
}

__device__ __forceinline__ float loss_elem(float Ev, float sv, float ov,
                                           float dv, float fv, int i, int j,
                                           float esc) {
  const float sp = (Ev > 0.f) ? (-0.1f * logf(Ev)) : 1e9f;
  const float ur = expf(-0.005f * sp);
  const float ub = expf(-0.01f * dv);
  const float choice = ur / (ur + ub);
  const float ug = fv * choice * (dv - 0.5f * sp);
  const float util = (ug > 0.f) ? (ug + 1.f) : expf(ug);  // elu + 1
  const float ent = sv * (((i == j) ? 1.f : 0.f) - sv);
  return sv * dv + util + esc * ent * ent + 10000.f * (sv * (1.f - ov));
}

// Final pass: E + C7*R7 (+ diag fixup C_{b-1}R_{b-1}) -> fused loss reduce.
__global__ __launch_bounds__(NTHR) void k_loss(
    const float* __restrict__ s, const float* __restrict__ o,
    const float* __restrict__ dI, const float* __restrict__ f,
    const int* __restrict__ ep, const float* __restrict__ E,
    const float* __restrict__ Cs, const float* __restrict__ Rs,
    float* __restrict__ out) {
  __shared__ float red[NTHR];
  const int tid = threadIdx.x;
  const int g = blockIdx.x * NTHR + tid;
  const int idx0 = g * 4;
  const int i = idx0 >> 9;
  const int j = idx0 & (NN - 1);
  const float* C7 = Cs + (size_t)7 * (NN * KP);
  const float* R7 = Rs + (size_t)7 * (KP * NN);
  float4 acc = *(const float4*)(E + idx0);
  {
    const float* crow = C7 + (size_t)i * KP;
    const float* rcol = R7 + j;
#pragma unroll 8
    for (int r = 0; r < KP; ++r) {
      const float cv = crow[r];
      const float4 rv = *(const float4*)(rcol + (size_t)r * NN);
      acc.x += cv * rv.x; acc.y += cv * rv.y;
      acc.z += cv * rv.z; acc.w += cv * rv.w;
    }
  }
  const int bi = i >> 6, bj = j >> 6;
  if (bi == bj && bi >= 1) {   // diag block: add the skipped C_{b-1}R_{b-1}
    const float* cf = Cs + (size_t)(bi - 1) * (NN * KP) + (size_t)i * KP;
    const float* rf = Rs + (size_t)(bi - 1) * (KP * NN) + j;
#pragma unroll 8
    for (int r = 0; r < KP; ++r) {
      const float cv = cf[r];
      const float4 rv = *(const float4*)(rf + (size_t)r * NN);
      acc.x += cv * rv.x; acc.y += cv * rv.y;
      acc.z += cv * rv.z; acc.w += cv * rv.w;
    }
  }
  const float4 sv = *(const float4*)(s + idx0);
  const float4 ov = *(const float4*)(o + idx0);
  const float4 dv = *(const float4*)(dI + idx0);
  const float4 fv = *(const float4*)(f + idx0);
  const int e = ep[0];
  const float esc = (e < 0) ? 0.f : (e < 10) ? 0.05f : (e < 50) ? 0.1f : 1.f;
  float lsum = loss_elem(acc.x, sv.x, ov.x, dv.x, fv.x, i, j + 0, esc)
             + loss_elem(acc.y, sv.y, ov.y, dv.y, fv.y, i, j + 1, esc)
             + loss_elem(acc.z, sv.z, ov.z, dv.z, fv.z, i, j + 2, esc)
             + loss_elem(acc.w, sv.w, ov.w, dv.w, fv.w, i, j + 3, esc);
  red[tid] = lsum;
  __syncthreads();
#pragma unroll
  for (int st = 128; st > 0; st >>= 1) {
    if (tid < st) red[tid] += red[tid + st];
    __syncthreads();
  }
  if (tid == 0) atomicAdd(out, red[0]);
}

extern "C" void kernel_launch(void* const* d_in, const int* in_sizes, int n_in,
                              void* d_out, int out_size, void* d_ws, size_t ws_size,
                              hipStream_t stream) {
  const float* s = (const float*)d_in[0];   // soft_adj
  const float* o = (const float*)d_in[1];   // original_adj
  const float* d = (const float*)d_in[2];   // distances
  const float* f = (const float*)d_in[3];   // flow
  const int* ep = (const int*)d_in[4];      // epoch

  float* E = (float*)d_ws;                  // 512*512
  float* Cs = E + NN * NN;                  // 8 x [512*64]
  float* Rs = Cs + NPANEL * NN * KP;        // 8 x [64*512]
  float* out = (float*)d_out;

  for (int p = 0; p < NPANEL; ++p)
    fw_phase<<<NBLK, NTHR, 0, stream>>>(s, d, E, Cs, Rs, out, p);
  k_loss<<<NBLK, NTHR, 0, stream>>>(s, o, d, f, ep, E, Cs, Rs, out);
}